// Round 6
// baseline (346.917 us; speedup 1.0000x reference)
//
#include <hip/hip_runtime.h>
#include <stdint.h>

#define NN   4096
#define KIN  256
#define NH   8
#define FD   64
#define HFD  512
#define NC   4            // j-chunks
#define BI   16           // i-rows per block in k3
#define JT   64           // j-tile
#define NT   ((NN / NC) / JT)   // 16

typedef __attribute__((ext_vector_type(4))) float  floatx4;
typedef __attribute__((ext_vector_type(8))) short  short8;

__device__ __forceinline__ unsigned short f2bf_rne(float x) {
    uint32_t u = __float_as_uint(x);
    u += 0x7FFFu + ((u >> 16) & 1u);
    return (unsigned short)(u >> 16);
}
__device__ __forceinline__ float bf2f(unsigned short b) {
    return __uint_as_float(((uint32_t)b) << 16);
}
// pack two fp32 -> two bf16 (truncate) into one dword: {hi[31:16], lo[31:16]}
__device__ __forceinline__ uint32_t packtrunc(float lo, float hi) {
    return (__float_as_uint(hi) & 0xFFFF0000u) | (__float_as_uint(lo) >> 16);
}

// ---- k_zero: capture-safe zero-init of out-accumulator and denominator ----
__global__ __launch_bounds__(256) void k_zero(float* __restrict__ outAcc,
                                              float* __restrict__ denA) {
    const int idx = blockIdx.x * 256 + threadIdx.x;
    const float4 z = make_float4(0.f, 0.f, 0.f, 0.f);
    if (idx < (NN * HFD) / 4) {
        *reinterpret_cast<float4*>(&outAcc[idx * 4]) = z;
    } else {
        const int q = idx - (NN * HFD) / 4;
        if (q < (NH * NN) / 4) *reinterpret_cast<float4*>(&denA[q * 4]) = z;
    }
}

// ---- k0: split h and W into bf16 hi/lo pairs; W also transposed to [HF][K] ----
__global__ __launch_bounds__(256) void k0_prep(
        const float* __restrict__ hmat, const float* __restrict__ Wmat,
        unsigned short* __restrict__ h_hi, unsigned short* __restrict__ h_lo,
        unsigned short* __restrict__ wt_hi, unsigned short* __restrict__ wt_lo) {
    const int bx = blockIdx.x, tid = threadIdx.x;
    if (bx < 1024) {                          // h: 4096x256 fp32 -> hi/lo bf16
        const int e0 = (bx * 256 + tid) * 4;
        const float4 v = *reinterpret_cast<const float4*>(&hmat[e0]);
        ushort4 hi, lo;
        hi.x = f2bf_rne(v.x); lo.x = f2bf_rne(v.x - bf2f(hi.x));
        hi.y = f2bf_rne(v.y); lo.y = f2bf_rne(v.y - bf2f(hi.y));
        hi.z = f2bf_rne(v.z); lo.z = f2bf_rne(v.z - bf2f(hi.z));
        hi.w = f2bf_rne(v.w); lo.w = f2bf_rne(v.w - bf2f(hi.w));
        *reinterpret_cast<ushort4*>(&h_hi[e0]) = hi;
        *reinterpret_cast<ushort4*>(&h_lo[e0]) = lo;
    } else {                                  // W: 256x512 -> Wt hi/lo [512][256]
        const int c = bx - 1024;              // output row (HF col of W)
        const float v = Wmat[(size_t)tid * HFD + c];
        const unsigned short hi = f2bf_rne(v);
        const unsigned short lo = f2bf_rne(v - bf2f(hi));
        wt_hi[c * KIN + tid] = hi;
        wt_lo[c * KIN + tid] = lo;
    }
}

// ---- k1: Wh via MFMA with bf16 hi/lo split (fp32-accurate); whbT + e tables ----
__global__ __launch_bounds__(256) void k1_front(
        const unsigned short* __restrict__ h_hi, const unsigned short* __restrict__ h_lo,
        const unsigned short* __restrict__ wt_hi, const unsigned short* __restrict__ wt_lo,
        const float* __restrict__ a_src, const float* __restrict__ a_dst,
        unsigned short* __restrict__ whbT,
        float* __restrict__ esrcT, float* __restrict__ edstT) {
    const int tid  = threadIdx.x;
    const int w    = tid >> 6;          // wave 0..3: 16-row slice
    const int lane = tid & 63;
    const int g = lane >> 4, lr = lane & 15;
    const int n0  = blockIdx.x * 64;
    const int hd  = blockIdx.y;
    const int hf0 = hd * FD;
    const int row = n0 + w * 16 + lr;   // A-fragment row
    floatx4 acc[4] = {};
    #pragma unroll
    for (int k0 = 0; k0 < KIN; k0 += 32) {
        const short8 ahi = *reinterpret_cast<const short8*>(&h_hi[(size_t)row * KIN + k0 + g * 8]);
        const short8 alo = *reinterpret_cast<const short8*>(&h_lo[(size_t)row * KIN + k0 + g * 8]);
        #pragma unroll
        for (int ni = 0; ni < 4; ++ni) {
            const size_t bo = (size_t)(hf0 + ni * 16 + lr) * KIN + k0 + g * 8;
            const short8 bhi = *reinterpret_cast<const short8*>(&wt_hi[bo]);
            const short8 blo = *reinterpret_cast<const short8*>(&wt_lo[bo]);
            acc[ni] = __builtin_amdgcn_mfma_f32_16x16x32_bf16(ahi, bhi, acc[ni], 0, 0, 0);
            acc[ni] = __builtin_amdgcn_mfma_f32_16x16x32_bf16(ahi, blo, acc[ni], 0, 0, 0);
            acc[ni] = __builtin_amdgcn_mfma_f32_16x16x32_bf16(alo, bhi, acc[ni], 0, 0, 0);
        }
    }
    // whbT bf16 [HF][N]; C/D layout col=lane&15, row=(lane>>4)*4+reg
    #pragma unroll
    for (int ni = 0; ni < 4; ++ni) {
        const int hf = hf0 + ni * 16 + lr;
        ushort4 o;
        o.x = f2bf_rne(acc[ni][0]); o.y = f2bf_rne(acc[ni][1]);
        o.z = f2bf_rne(acc[ni][2]); o.w = f2bf_rne(acc[ni][3]);
        *reinterpret_cast<ushort4*>(&whbT[(size_t)hf * NN + n0 + w * 16 + g * 4]) = o;
    }
    // e_src/e_dst from fp32 accumulators: per-lane partial + 16-lane xor reduce
    float asv[4], adv[4];
    #pragma unroll
    for (int ni = 0; ni < 4; ++ni) {
        asv[ni] = a_src[hf0 + ni * 16 + lr];
        adv[ni] = a_dst[hf0 + ni * 16 + lr];
    }
    #pragma unroll
    for (int r = 0; r < 4; ++r) {
        float ps = 0.f, pd = 0.f;
        #pragma unroll
        for (int ni = 0; ni < 4; ++ni) { ps += acc[ni][r] * asv[ni]; pd += acc[ni][r] * adv[ni]; }
        #pragma unroll
        for (int off = 1; off < 16; off <<= 1) {
            ps += __shfl_xor(ps, off, 64);
            pd += __shfl_xor(pd, off, 64);
        }
        if (lr == 0) {
            esrcT[hd * NN + n0 + w * 16 + g * 4 + r] = ps;
            edstT[hd * NN + n0 + w * 16 + g * 4 + r] = pd;
        }
    }
}

// ---- k2: per-head max(e_dst) and the four exp tables ----
__global__ __launch_bounds__(256) void k2_tables(
        const float* __restrict__ esrcT, const float* __restrict__ edstT,
        float* __restrict__ es1T, float* __restrict__ es2T,
        float* __restrict__ ed1T, float* __restrict__ ed2T) {
    __shared__ float red[256];
    const int hd = blockIdx.x, tid = threadIdx.x;
    float m = -1e30f;
    for (int n = tid; n < NN; n += 256) m = fmaxf(m, edstT[hd * NN + n]);
    red[tid] = m;
    __syncthreads();
    for (int s = 128; s > 0; s >>= 1) {
        if (tid < s) red[tid] = fmaxf(red[tid], red[tid + s]);
        __syncthreads();
    }
    const float maxd = red[0];
    for (int n = tid; n < NN; n += 256) {
        const float ed = edstT[hd * NN + n];
        ed1T[hd * NN + n] = __expf(ed);
        ed2T[hd * NN + n] = __expf(0.2f * ed);
        const float es = esrcT[hd * NN + n];
        const float t  = es + maxd;
        const float M  = fmaxf(t, 0.2f * t);      // lrelu(es + max_j ed) >= any score
        es1T[hd * NN + n] = __expf(es - M);
        es2T[hd * NN + n] = __expf(0.2f * es - M);
    }
}

// ---- k3: fused masked-softmax aggregation; 1024 blocks, 1 barrier/iter ----
__global__ __launch_bounds__(512, 8) void k3_attn(
        const int* __restrict__ adj, const unsigned short* __restrict__ whbT,
        const float* __restrict__ es1T, const float* __restrict__ es2T,
        const float* __restrict__ ed1T, const float* __restrict__ ed2T,
        float* __restrict__ outAcc, float* __restrict__ denA) {
    __shared__ uint32_t amask[2][BI][32];   // double-buffered swizzled mask words
    const int tid  = threadIdx.x;
    const int lane = tid & 63;
    const int wid  = tid >> 6;              // head
    const int iblk = blockIdx.x & 255;
    const int jc   = blockIdx.x >> 8;
    const int i0   = iblk * BI;
    const int jbase = jc * (NN / NC);
    const int g  = lane >> 4;
    const int lr = lane & 15;

    const float es1 = es1T[wid * NN + i0 + lr];
    const float es2 = es2T[wid * NN + i0 + lr];

    floatx4 acc[4] = {};
    floatx4 accd = {};
    short8 ones;          // B with column 0 = 1.0bf16 -> row-sum (denominator)
    {
        const short ov = (lr == 0) ? (short)0x3F80 : (short)0;
        #pragma unroll
        for (int e = 0; e < 8; ++e) ones[e] = ov;
    }

    // staging: 512 threads -> 16 rows x 32 mask dwords, XOR-swizzled 16B blocks
    const int sr = tid >> 5, sw = tid & 31;
    const int spos = (sw & 3) | ((((sw >> 2) ^ (sr & 7)) & 7) << 2);
    const int* aptr = &adj[(size_t)(i0 + sr) * NN + sw * 2];

    int2 R = *reinterpret_cast<const int2*>(aptr + jbase);             // tile 0
    amask[0][sr][spos] = (R.x ? 0xFFFFu : 0u) | (R.y ? 0xFFFF0000u : 0u);
    R = *reinterpret_cast<const int2*>(aptr + jbase + JT);             // tile 1
    __syncthreads();

    for (int t = 0; t < NT; ++t) {
        const int j0  = jbase + t * JT;
        const int buf = t & 1;
        if (t + 1 < NT)
            amask[(t + 1) & 1][sr][spos] = (R.x ? 0xFFFFu : 0u) | (R.y ? 0xFFFF0000u : 0u);
        if (t + 2 < NT)
            R = *reinterpret_cast<const int2*>(aptr + jbase + (t + 2) * JT);

        short8 bfrag[2][4];
        #pragma unroll
        for (int ks = 0; ks < 2; ++ks)
            #pragma unroll
            for (int ni = 0; ni < 4; ++ni)
                bfrag[ks][ni] = *reinterpret_cast<const short8*>(
                    &whbT[(size_t)(wid * FD + ni * 16 + lr) * NN + j0 + ks * 32 + g * 8]);

        #pragma unroll
        for (int ks = 0; ks < 2; ++ks) {
            const int jo = wid * NN + j0 + ks * 32 + g * 8;
            const float4 e1a = *reinterpret_cast<const float4*>(&ed1T[jo]);
            const float4 e1b = *reinterpret_cast<const float4*>(&ed1T[jo + 4]);
            const float4 e2a = *reinterpret_cast<const float4*>(&ed2T[jo]);
            const float4 e2b = *reinterpret_cast<const float4*>(&ed2T[jo + 4]);
            const int pb = (((ks * 4 + g) ^ (lr & 7)) & 7) * 4;
            const uint4 msk = *reinterpret_cast<const uint4*>(&amask[buf][lr][pb]);
            union { uint32_t wd[4]; short8 s8; } pu;
            pu.wd[0] = packtrunc(fmaxf(es1 * e1a.x, es2 * e2a.x),
                                 fmaxf(es1 * e1a.y, es2 * e2a.y)) & msk.x;
            pu.wd[1] = packtrunc(fmaxf(es1 * e1a.z, es2 * e2a.z),
                                 fmaxf(es1 * e1a.w, es2 * e2a.w)) & msk.y;
            pu.wd[2] = packtrunc(fmaxf(es1 * e1b.x, es2 * e2b.x),
                                 fmaxf(es1 * e1b.y, es2 * e2b.y)) & msk.z;
            pu.wd[3] = packtrunc(fmaxf(es1 * e1b.z, es2 * e2b.z),
                                 fmaxf(es1 * e1b.w, es2 * e2b.w)) & msk.w;
            #pragma unroll
            for (int ni = 0; ni < 4; ++ni)
                acc[ni] = __builtin_amdgcn_mfma_f32_16x16x32_bf16(
                    pu.s8, bfrag[ks][ni], acc[ni], 0, 0, 0);
            accd = __builtin_amdgcn_mfma_f32_16x16x32_bf16(pu.s8, ones, accd, 0, 0, 0);
        }
        __syncthreads();
    }

    // epilogue: accumulate partial num/den via device-scope fp32 atomics
    #pragma unroll
    for (int ni = 0; ni < 4; ++ni)
        #pragma unroll
        for (int r = 0; r < 4; ++r)
            atomicAdd(&outAcc[(size_t)(i0 + g * 4 + r) * HFD + wid * FD + ni * 16 + lr],
                      acc[ni][r]);
    if (lr == 0) {
        #pragma unroll
        for (int r = 0; r < 4; ++r)
            atomicAdd(&denA[wid * NN + i0 + g * 4 + r], accd[r]);
    }
}

// ---- k4: in-place normalize + bias ----
__global__ __launch_bounds__(256) void k4_norm(
        float* __restrict__ out, const float* __restrict__ denA,
        const float* __restrict__ bias) {
    const int idx = blockIdx.x * 256 + threadIdx.x;
    const int e0 = idx * 4;
    const int i  = e0 >> 9;
    const int hf = e0 & 511;
    const int hd = hf >> 6;
    const float4 s = *reinterpret_cast<const float4*>(&out[e0]);
    const float inv = 1.0f / denA[hd * NN + i];
    const float4 b = *reinterpret_cast<const float4*>(&bias[hf]);
    float4 o;
    o.x = s.x * inv + b.x; o.y = s.y * inv + b.y;
    o.z = s.z * inv + b.z; o.w = s.w * inv + b.w;
    *reinterpret_cast<float4*>(&out[e0]) = o;
}

extern "C" void kernel_launch(void* const* d_in, const int* in_sizes, int n_in,
                              void* d_out, int out_size, void* d_ws, size_t ws_size,
                              hipStream_t stream) {
    const float* hmat  = (const float*)d_in[0];
    const int*   adj   = (const int*)d_in[1];
    const float* Wmat  = (const float*)d_in[2];
    const float* a_src = (const float*)d_in[3];
    const float* a_dst = (const float*)d_in[4];
    const float* bias  = (const float*)d_in[5];
    float* out = (float*)d_out;

    char* ws = (char*)d_ws;
    unsigned short* whbT = (unsigned short*)ws;               // 4 MiB bf16 [HF][N]
    float* esrcT = (float*)(ws + (4u << 20));                 // 6 x 128 KiB
    float* edstT = esrcT + NH * NN;
    float* es1T  = edstT + NH * NN;
    float* es2T  = es1T + NH * NN;
    float* ed1T  = es2T + NH * NN;
    float* ed2T  = ed1T + NH * NN;
    unsigned short* h_hi = (unsigned short*)(ed2T + NH * NN); // 2 MiB
    unsigned short* h_lo = h_hi + (size_t)NN * KIN;           // 2 MiB
    unsigned short* wt_hi = h_lo + (size_t)NN * KIN;          // 256 KiB
    unsigned short* wt_lo = wt_hi + (size_t)KIN * HFD;        // 256 KiB
    float* denA = (float*)(wt_lo + (size_t)KIN * HFD);        // 128 KiB

    k_zero<<<dim3((NN * HFD / 4 + NH * NN / 4 + 255) / 256), 256, 0, stream>>>(out, denA);
    k0_prep<<<dim3(1536), 256, 0, stream>>>(hmat, Wmat, h_hi, h_lo, wt_hi, wt_lo);
    k1_front<<<dim3(64, 8), 256, 0, stream>>>(h_hi, h_lo, wt_hi, wt_lo, a_src, a_dst,
                                              whbT, esrcT, edstT);
    k2_tables<<<dim3(NH), 256, 0, stream>>>(esrcT, edstT, es1T, es2T, ed1T, ed2T);
    k3_attn<<<dim3(256 * NC), 512, 0, stream>>>(adj, whbT, es1T, es2T, ed1T, ed2T, out, denA);
    k4_norm<<<dim3((NN * HFD / 4) / 256), 256, 0, stream>>>(out, denA, bias);
}

// Round 9
// 332.074 us; speedup vs baseline: 1.0447x; 1.0447x over previous
//
#include <hip/hip_runtime.h>
#include <stdint.h>

#define NN   4096
#define KIN  256
#define NH   8
#define FD   64
#define HFD  512
#define NC   4            // j-chunks
#define BI   16           // i-rows per block in k3
#define JT   64           // j-tile
#define NT   ((NN / NC) / JT)   // 16

typedef __attribute__((ext_vector_type(4))) float  floatx4;
typedef __attribute__((ext_vector_type(8))) short  short8;

__device__ __forceinline__ unsigned short f2bf_rne(float x) {
    uint32_t u = __float_as_uint(x);
    u += 0x7FFFu + ((u >> 16) & 1u);
    return (unsigned short)(u >> 16);
}
__device__ __forceinline__ float bf2f(unsigned short b) {
    return __uint_as_float(((uint32_t)b) << 16);
}
// pack two fp32 -> two bf16 (truncate) into one dword: {hi[31:16], lo[31:16]}
__device__ __forceinline__ uint32_t packtrunc(float lo, float hi) {
    return (__float_as_uint(hi) & 0xFFFF0000u) | (__float_as_uint(lo) >> 16);
}

// ---- k0: split h and W into bf16 hi/lo pairs; W also transposed to [HF][K] ----
__global__ __launch_bounds__(256) void k0_prep(
        const float* __restrict__ hmat, const float* __restrict__ Wmat,
        unsigned short* __restrict__ h_hi, unsigned short* __restrict__ h_lo,
        unsigned short* __restrict__ wt_hi, unsigned short* __restrict__ wt_lo) {
    const int bx = blockIdx.x, tid = threadIdx.x;
    if (bx < 1024) {                          // h: 4096x256 fp32 -> hi/lo bf16
        const int e0 = (bx * 256 + tid) * 4;
        const float4 v = *reinterpret_cast<const float4*>(&hmat[e0]);
        ushort4 hi, lo;
        hi.x = f2bf_rne(v.x); lo.x = f2bf_rne(v.x - bf2f(hi.x));
        hi.y = f2bf_rne(v.y); lo.y = f2bf_rne(v.y - bf2f(hi.y));
        hi.z = f2bf_rne(v.z); lo.z = f2bf_rne(v.z - bf2f(hi.z));
        hi.w = f2bf_rne(v.w); lo.w = f2bf_rne(v.w - bf2f(hi.w));
        *reinterpret_cast<ushort4*>(&h_hi[e0]) = hi;
        *reinterpret_cast<ushort4*>(&h_lo[e0]) = lo;
    } else {                                  // W: 256x512 -> Wt hi/lo [512][256]
        const int c = bx - 1024;              // output row (HF col of W)
        const float v = Wmat[(size_t)tid * HFD + c];
        const unsigned short hi = f2bf_rne(v);
        const unsigned short lo = f2bf_rne(v - bf2f(hi));
        wt_hi[c * KIN + tid] = hi;
        wt_lo[c * KIN + tid] = lo;
    }
}

// ---- k1: Wh via MFMA with bf16 hi/lo split (fp32-accurate); whbT + e tables ----
__global__ __launch_bounds__(256) void k1_front(
        const unsigned short* __restrict__ h_hi, const unsigned short* __restrict__ h_lo,
        const unsigned short* __restrict__ wt_hi, const unsigned short* __restrict__ wt_lo,
        const float* __restrict__ a_src, const float* __restrict__ a_dst,
        unsigned short* __restrict__ whbT,
        float* __restrict__ esrcT, float* __restrict__ edstT) {
    const int tid  = threadIdx.x;
    const int w    = tid >> 6;          // wave 0..3: 16-row slice
    const int lane = tid & 63;
    const int g = lane >> 4, lr = lane & 15;
    const int n0  = blockIdx.x * 64;
    const int hd  = blockIdx.y;
    const int hf0 = hd * FD;
    const int row = n0 + w * 16 + lr;   // A-fragment row
    floatx4 acc[4] = {};
    #pragma unroll
    for (int k0 = 0; k0 < KIN; k0 += 32) {
        const short8 ahi = *reinterpret_cast<const short8*>(&h_hi[(size_t)row * KIN + k0 + g * 8]);
        const short8 alo = *reinterpret_cast<const short8*>(&h_lo[(size_t)row * KIN + k0 + g * 8]);
        #pragma unroll
        for (int ni = 0; ni < 4; ++ni) {
            const size_t bo = (size_t)(hf0 + ni * 16 + lr) * KIN + k0 + g * 8;
            const short8 bhi = *reinterpret_cast<const short8*>(&wt_hi[bo]);
            const short8 blo = *reinterpret_cast<const short8*>(&wt_lo[bo]);
            acc[ni] = __builtin_amdgcn_mfma_f32_16x16x32_bf16(ahi, bhi, acc[ni], 0, 0, 0);
            acc[ni] = __builtin_amdgcn_mfma_f32_16x16x32_bf16(ahi, blo, acc[ni], 0, 0, 0);
            acc[ni] = __builtin_amdgcn_mfma_f32_16x16x32_bf16(alo, bhi, acc[ni], 0, 0, 0);
        }
    }
    // whbT bf16 [HF][N]; C/D layout col=lane&15, row=(lane>>4)*4+reg
    #pragma unroll
    for (int ni = 0; ni < 4; ++ni) {
        const int hf = hf0 + ni * 16 + lr;
        ushort4 o;
        o.x = f2bf_rne(acc[ni][0]); o.y = f2bf_rne(acc[ni][1]);
        o.z = f2bf_rne(acc[ni][2]); o.w = f2bf_rne(acc[ni][3]);
        *reinterpret_cast<ushort4*>(&whbT[(size_t)hf * NN + n0 + w * 16 + g * 4]) = o;
    }
    // e_src/e_dst from fp32 accumulators: per-lane partial + 16-lane xor reduce
    float asv[4], adv[4];
    #pragma unroll
    for (int ni = 0; ni < 4; ++ni) {
        asv[ni] = a_src[hf0 + ni * 16 + lr];
        adv[ni] = a_dst[hf0 + ni * 16 + lr];
    }
    #pragma unroll
    for (int r = 0; r < 4; ++r) {
        float ps = 0.f, pd = 0.f;
        #pragma unroll
        for (int ni = 0; ni < 4; ++ni) { ps += acc[ni][r] * asv[ni]; pd += acc[ni][r] * adv[ni]; }
        #pragma unroll
        for (int off = 1; off < 16; off <<= 1) {
            ps += __shfl_xor(ps, off, 64);
            pd += __shfl_xor(pd, off, 64);
        }
        if (lr == 0) {
            esrcT[hd * NN + n0 + w * 16 + g * 4 + r] = ps;
            edstT[hd * NN + n0 + w * 16 + g * 4 + r] = pd;
        }
    }
}

// ---- k2: per-head max(e_dst) and the four exp tables ----
__global__ __launch_bounds__(256) void k2_tables(
        const float* __restrict__ esrcT, const float* __restrict__ edstT,
        float* __restrict__ es1T, float* __restrict__ es2T,
        float* __restrict__ ed1T, float* __restrict__ ed2T) {
    __shared__ float red[256];
    const int hd = blockIdx.x, tid = threadIdx.x;
    float m = -1e30f;
    for (int n = tid; n < NN; n += 256) m = fmaxf(m, edstT[hd * NN + n]);
    red[tid] = m;
    __syncthreads();
    for (int s = 128; s > 0; s >>= 1) {
        if (tid < s) red[tid] = fmaxf(red[tid], red[tid + s]);
        __syncthreads();
    }
    const float maxd = red[0];
    for (int n = tid; n < NN; n += 256) {
        const float ed = edstT[hd * NN + n];
        ed1T[hd * NN + n] = __expf(ed);
        ed2T[hd * NN + n] = __expf(0.2f * ed);
        const float es = esrcT[hd * NN + n];
        const float t  = es + maxd;
        const float M  = fmaxf(t, 0.2f * t);      // lrelu(es + max_j ed) >= any score
        es1T[hd * NN + n] = __expf(es - M);
        es2T[hd * NN + n] = __expf(0.2f * es - M);
    }
}

// ---- k3: fused masked-softmax aggregation; XCD-local jc, stores (no atomics) ----
__global__ __launch_bounds__(512, 8) void k3_attn(
        const int* __restrict__ adj, const unsigned short* __restrict__ whbT,
        const float* __restrict__ es1T, const float* __restrict__ es2T,
        const float* __restrict__ ed1T, const float* __restrict__ ed2T,
        float* __restrict__ numP, float* __restrict__ denP) {
    __shared__ uint32_t amask[2][BI][32];   // double-buffered swizzled mask words
    const int tid  = threadIdx.x;
    const int lane = tid & 63;
    const int wid  = tid >> 6;              // head
    // XCD-locality remap: bx%8 ~ XCD (round-robin dispatch). All blocks on one
    // XCD share jc -> whbT j-slice (1 MiB) + table slices stay L2-resident.
    // Bijective over 1024 blocks: jc = xcd&3, iblk = q + 128*(xcd>>2).
    const int bx   = blockIdx.x;
    const int xcd  = bx & 7;
    const int q    = bx >> 3;               // 0..127
    const int jc   = xcd & 3;
    const int iblk = q + ((xcd >> 2) << 7); // 0..255
    const int i0   = iblk * BI;
    const int jbase = jc * (NN / NC);
    const int g  = lane >> 4;
    const int lr = lane & 15;

    const float es1 = es1T[wid * NN + i0 + lr];
    const float es2 = es2T[wid * NN + i0 + lr];

    floatx4 acc[4] = {};
    floatx4 accd = {};
    short8 ones;          // B with column 0 = 1.0bf16 -> row-sum (denominator)
    {
        const short ov = (lr == 0) ? (short)0x3F80 : (short)0;
        #pragma unroll
        for (int e = 0; e < 8; ++e) ones[e] = ov;
    }

    // staging: 512 threads -> 16 rows x 32 mask dwords, XOR-swizzled 16B blocks
    const int sr = tid >> 5, sw = tid & 31;
    const int spos = (sw & 3) | ((((sw >> 2) ^ (sr & 7)) & 7) << 2);
    const int* aptr = &adj[(size_t)(i0 + sr) * NN + sw * 2];

    int2 R = *reinterpret_cast<const int2*>(aptr + jbase);             // tile 0
    amask[0][sr][spos] = (R.x ? 0xFFFFu : 0u) | (R.y ? 0xFFFF0000u : 0u);
    R = *reinterpret_cast<const int2*>(aptr + jbase + JT);             // tile 1
    __syncthreads();

    for (int t = 0; t < NT; ++t) {
        const int j0  = jbase + t * JT;
        const int buf = t & 1;
        if (t + 1 < NT)
            amask[(t + 1) & 1][sr][spos] = (R.x ? 0xFFFFu : 0u) | (R.y ? 0xFFFF0000u : 0u);
        if (t + 2 < NT)
            R = *reinterpret_cast<const int2*>(aptr + jbase + (t + 2) * JT);

        short8 bfrag[2][4];
        #pragma unroll
        for (int ks = 0; ks < 2; ++ks)
            #pragma unroll
            for (int ni = 0; ni < 4; ++ni)
                bfrag[ks][ni] = *reinterpret_cast<const short8*>(
                    &whbT[(size_t)(wid * FD + ni * 16 + lr) * NN + j0 + ks * 32 + g * 8]);

        #pragma unroll
        for (int ks = 0; ks < 2; ++ks) {
            const int jo = wid * NN + j0 + ks * 32 + g * 8;
            const float4 e1a = *reinterpret_cast<const float4*>(&ed1T[jo]);
            const float4 e1b = *reinterpret_cast<const float4*>(&ed1T[jo + 4]);
            const float4 e2a = *reinterpret_cast<const float4*>(&ed2T[jo]);
            const float4 e2b = *reinterpret_cast<const float4*>(&ed2T[jo + 4]);
            const int pb = (((ks * 4 + g) ^ (lr & 7)) & 7) * 4;
            const uint4 msk = *reinterpret_cast<const uint4*>(&amask[buf][lr][pb]);
            union { uint32_t wd[4]; short8 s8; } pu;
            pu.wd[0] = packtrunc(fmaxf(es1 * e1a.x, es2 * e2a.x),
                                 fmaxf(es1 * e1a.y, es2 * e2a.y)) & msk.x;
            pu.wd[1] = packtrunc(fmaxf(es1 * e1a.z, es2 * e2a.z),
                                 fmaxf(es1 * e1a.w, es2 * e2a.w)) & msk.y;
            pu.wd[2] = packtrunc(fmaxf(es1 * e1b.x, es2 * e2b.x),
                                 fmaxf(es1 * e1b.y, es2 * e2b.y)) & msk.z;
            pu.wd[3] = packtrunc(fmaxf(es1 * e1b.z, es2 * e2b.z),
                                 fmaxf(es1 * e1b.w, es2 * e2b.w)) & msk.w;
            #pragma unroll
            for (int ni = 0; ni < 4; ++ni)
                acc[ni] = __builtin_amdgcn_mfma_f32_16x16x32_bf16(
                    pu.s8, bfrag[ks][ni], acc[ni], 0, 0, 0);
            accd = __builtin_amdgcn_mfma_f32_16x16x32_bf16(pu.s8, ones, accd, 0, 0, 0);
        }
        __syncthreads();
    }

    // epilogue: plain stores of per-chunk partials (no atomics)
    #pragma unroll
    for (int ni = 0; ni < 4; ++ni)
        #pragma unroll
        for (int r = 0; r < 4; ++r)
            numP[((size_t)jc * NN + i0 + g * 4 + r) * HFD + wid * FD + ni * 16 + lr] =
                acc[ni][r];
    if (lr == 0) {
        #pragma unroll
        for (int r = 0; r < 4; ++r)
            denP[((size_t)jc * NH + wid) * NN + i0 + g * 4 + r] = accd[r];
    }
}

// ---- k4: combine chunk partials, normalize, add bias ----
__global__ __launch_bounds__(256) void k4_reduce(
        const float* __restrict__ numP, const float* __restrict__ denP,
        const float* __restrict__ bias, float* __restrict__ out) {
    const int idx = blockIdx.x * 256 + threadIdx.x;
    const int e0 = idx * 4;
    const int i  = e0 >> 9;
    const int hf = e0 & 511;
    const int hd = hf >> 6;
    float4 s = make_float4(0.f, 0.f, 0.f, 0.f);
    float d = 0.f;
    #pragma unroll
    for (int c = 0; c < NC; ++c) {
        const float4 v = *reinterpret_cast<const float4*>(&numP[((size_t)c * NN + i) * HFD + hf]);
        s.x += v.x; s.y += v.y; s.z += v.z; s.w += v.w;
        d += denP[((size_t)c * NH + hd) * NN + i];
    }
    const float inv = 1.0f / d;
    const float4 b = *reinterpret_cast<const float4*>(&bias[hf]);
    float4 o;
    o.x = s.x * inv + b.x; o.y = s.y * inv + b.y;
    o.z = s.z * inv + b.z; o.w = s.w * inv + b.w;
    *reinterpret_cast<float4*>(&out[(size_t)i * HFD + hf]) = o;
}

extern "C" void kernel_launch(void* const* d_in, const int* in_sizes, int n_in,
                              void* d_out, int out_size, void* d_ws, size_t ws_size,
                              hipStream_t stream) {
    const float* hmat  = (const float*)d_in[0];
    const int*   adj   = (const int*)d_in[1];
    const float* Wmat  = (const float*)d_in[2];
    const float* a_src = (const float*)d_in[3];
    const float* a_dst = (const float*)d_in[4];
    const float* bias  = (const float*)d_in[5];
    float* out = (float*)d_out;

    char* ws = (char*)d_ws;
    unsigned short* whbT = (unsigned short*)ws;               // 4 MiB bf16 [HF][N]
    float* esrcT = (float*)(ws + (4u << 20));                 // 6 x 128 KiB tables
    float* edstT = esrcT + NH * NN;
    float* es1T  = edstT + NH * NN;
    float* es2T  = es1T + NH * NN;
    float* ed1T  = es2T + NH * NN;
    float* ed2T  = ed1T + NH * NN;
    float* numP  = ed2T + NH * NN;                            // 32 MiB (NC*N*HF)
    float* denP  = numP + (size_t)NC * NN * HFD;              // 512 KiB
    // prep buffers alias numP's first 4.5 MiB (dead after k1; k3 overwrites)
    unsigned short* h_hi = (unsigned short*)numP;             // 2 MiB
    unsigned short* h_lo = h_hi + (size_t)NN * KIN;           // 2 MiB
    unsigned short* wt_hi = h_lo + (size_t)NN * KIN;          // 256 KiB
    unsigned short* wt_lo = wt_hi + (size_t)KIN * HFD;        // 256 KiB

    k0_prep<<<dim3(1536), 256, 0, stream>>>(hmat, Wmat, h_hi, h_lo, wt_hi, wt_lo);
    k1_front<<<dim3(64, 8), 256, 0, stream>>>(h_hi, h_lo, wt_hi, wt_lo, a_src, a_dst,
                                              whbT, esrcT, edstT);
    k2_tables<<<dim3(NH), 256, 0, stream>>>(esrcT, edstT, es1T, es2T, ed1T, ed2T);
    k3_attn<<<dim3(256 * NC), 512, 0, stream>>>(adj, whbT, es1T, es2T, ed1T, ed2T, numP, denP);
    k4_reduce<<<dim3((NN * HFD / 4) / 256), 256, 0, stream>>>(numP, denP, bias, out);
}

// Round 10
// 282.489 us; speedup vs baseline: 1.2281x; 1.1755x over previous
//
#include <hip/hip_runtime.h>
#include <stdint.h>

#define NN   4096
#define KIN  256
#define NH   8
#define FD   64
#define HFD  512
#define BI   16
#define JT   64
#define NTILES (NN / JT)   // 64

typedef __attribute__((ext_vector_type(4))) float  floatx4;
typedef __attribute__((ext_vector_type(8))) short  short8;

__device__ __forceinline__ unsigned short f2bf_rne(float x) {
    uint32_t u = __float_as_uint(x);
    u += 0x7FFFu + ((u >> 16) & 1u);
    return (unsigned short)(u >> 16);
}
__device__ __forceinline__ float bf2f(unsigned short b) {
    return __uint_as_float(((uint32_t)b) << 16);
}
// pack two fp32 -> two bf16 (truncate) into one dword: {hi[31:16], lo[31:16]}
__device__ __forceinline__ uint32_t packtrunc(float lo, float hi) {
    return (__float_as_uint(hi) & 0xFFFF0000u) | (__float_as_uint(lo) >> 16);
}
// expand bit pair (2n, 2n+1) of byte b into two halfword masks
__device__ __forceinline__ uint32_t bit2mask(uint32_t b, int n) {
    return (((b >> (2 * n)) & 1u) ? 0x0000FFFFu : 0u) |
           (((b >> (2 * n + 1)) & 1u) ? 0xFFFF0000u : 0u);
}

// ---- k0: h/W bf16 hi-lo split + adj -> 2 MiB bitmask (perfectly streamed) ----
__global__ __launch_bounds__(256) void k0_prep(
        const float* __restrict__ hmat, const float* __restrict__ Wmat,
        const int* __restrict__ adj,
        unsigned short* __restrict__ h_hi, unsigned short* __restrict__ h_lo,
        unsigned short* __restrict__ wt_hi, unsigned short* __restrict__ wt_lo,
        uint32_t* __restrict__ bm) {
    const int bx = blockIdx.x, tid = threadIdx.x;
    if (bx < 1024) {                          // h: 4096x256 fp32 -> hi/lo bf16
        const int e0 = (bx * 256 + tid) * 4;
        const float4 v = *reinterpret_cast<const float4*>(&hmat[e0]);
        ushort4 hi, lo;
        hi.x = f2bf_rne(v.x); lo.x = f2bf_rne(v.x - bf2f(hi.x));
        hi.y = f2bf_rne(v.y); lo.y = f2bf_rne(v.y - bf2f(hi.y));
        hi.z = f2bf_rne(v.z); lo.z = f2bf_rne(v.z - bf2f(hi.z));
        hi.w = f2bf_rne(v.w); lo.w = f2bf_rne(v.w - bf2f(hi.w));
        *reinterpret_cast<ushort4*>(&h_hi[e0]) = hi;
        *reinterpret_cast<ushort4*>(&h_lo[e0]) = lo;
    } else if (bx < 1536) {                   // W: 256x512 -> Wt hi/lo [512][256]
        const int c = bx - 1024;
        const float v = Wmat[(size_t)tid * HFD + c];
        const unsigned short hi = f2bf_rne(v);
        const unsigned short lo = f2bf_rne(v - bf2f(hi));
        wt_hi[c * KIN + tid] = hi;
        wt_lo[c * KIN + tid] = lo;
    } else {                                  // adj -> bitmask: 1 word / thread
        const int widx = (bx - 1536) * 256 + tid;   // 0..524287
        const size_t base = (size_t)widx * 32;
        uint32_t m = 0;
        #pragma unroll
        for (int u = 0; u < 8; ++u) {
            const int4 a = *reinterpret_cast<const int4*>(&adj[base + u * 4]);
            m |= (a.x ? 1u : 0u) << (u * 4 + 0);
            m |= (a.y ? 1u : 0u) << (u * 4 + 1);
            m |= (a.z ? 1u : 0u) << (u * 4 + 2);
            m |= (a.w ? 1u : 0u) << (u * 4 + 3);
        }
        bm[widx] = m;
    }
}

// ---- k1: Wh via MFMA with bf16 hi/lo split (fp32-accurate); whbT + e tables ----
__global__ __launch_bounds__(256) void k1_front(
        const unsigned short* __restrict__ h_hi, const unsigned short* __restrict__ h_lo,
        const unsigned short* __restrict__ wt_hi, const unsigned short* __restrict__ wt_lo,
        const float* __restrict__ a_src, const float* __restrict__ a_dst,
        unsigned short* __restrict__ whbT,
        float* __restrict__ esrcT, float* __restrict__ edstT) {
    const int tid  = threadIdx.x;
    const int w    = tid >> 6;          // wave 0..3: 16-row slice
    const int lane = tid & 63;
    const int g = lane >> 4, lr = lane & 15;
    const int n0  = blockIdx.x * 64;
    const int hd  = blockIdx.y;
    const int hf0 = hd * FD;
    const int row = n0 + w * 16 + lr;   // A-fragment row
    floatx4 acc[4] = {};
    #pragma unroll
    for (int k0 = 0; k0 < KIN; k0 += 32) {
        const short8 ahi = *reinterpret_cast<const short8*>(&h_hi[(size_t)row * KIN + k0 + g * 8]);
        const short8 alo = *reinterpret_cast<const short8*>(&h_lo[(size_t)row * KIN + k0 + g * 8]);
        #pragma unroll
        for (int ni = 0; ni < 4; ++ni) {
            const size_t bo = (size_t)(hf0 + ni * 16 + lr) * KIN + k0 + g * 8;
            const short8 bhi = *reinterpret_cast<const short8*>(&wt_hi[bo]);
            const short8 blo = *reinterpret_cast<const short8*>(&wt_lo[bo]);
            acc[ni] = __builtin_amdgcn_mfma_f32_16x16x32_bf16(ahi, bhi, acc[ni], 0, 0, 0);
            acc[ni] = __builtin_amdgcn_mfma_f32_16x16x32_bf16(ahi, blo, acc[ni], 0, 0, 0);
            acc[ni] = __builtin_amdgcn_mfma_f32_16x16x32_bf16(alo, bhi, acc[ni], 0, 0, 0);
        }
    }
    // whbT bf16 [HF][N]; C/D layout col=lane&15, row=(lane>>4)*4+reg
    #pragma unroll
    for (int ni = 0; ni < 4; ++ni) {
        const int hf = hf0 + ni * 16 + lr;
        ushort4 o;
        o.x = f2bf_rne(acc[ni][0]); o.y = f2bf_rne(acc[ni][1]);
        o.z = f2bf_rne(acc[ni][2]); o.w = f2bf_rne(acc[ni][3]);
        *reinterpret_cast<ushort4*>(&whbT[(size_t)hf * NN + n0 + w * 16 + g * 4]) = o;
    }
    // e_src/e_dst from fp32 accumulators: per-lane partial + 16-lane xor reduce
    float asv[4], adv[4];
    #pragma unroll
    for (int ni = 0; ni < 4; ++ni) {
        asv[ni] = a_src[hf0 + ni * 16 + lr];
        adv[ni] = a_dst[hf0 + ni * 16 + lr];
    }
    #pragma unroll
    for (int r = 0; r < 4; ++r) {
        float ps = 0.f, pd = 0.f;
        #pragma unroll
        for (int ni = 0; ni < 4; ++ni) { ps += acc[ni][r] * asv[ni]; pd += acc[ni][r] * adv[ni]; }
        #pragma unroll
        for (int off = 1; off < 16; off <<= 1) {
            ps += __shfl_xor(ps, off, 64);
            pd += __shfl_xor(pd, off, 64);
        }
        if (lr == 0) {
            esrcT[hd * NN + n0 + w * 16 + g * 4 + r] = ps;
            edstT[hd * NN + n0 + w * 16 + g * 4 + r] = pd;
        }
    }
}

// ---- k2: per-head max(e_dst) and the four exp tables ----
__global__ __launch_bounds__(256) void k2_tables(
        const float* __restrict__ esrcT, const float* __restrict__ edstT,
        float* __restrict__ es1T, float* __restrict__ es2T,
        float* __restrict__ ed1T, float* __restrict__ ed2T) {
    __shared__ float red[256];
    const int hd = blockIdx.x, tid = threadIdx.x;
    float m = -1e30f;
    for (int n = tid; n < NN; n += 256) m = fmaxf(m, edstT[hd * NN + n]);
    red[tid] = m;
    __syncthreads();
    for (int s = 128; s > 0; s >>= 1) {
        if (tid < s) red[tid] = fmaxf(red[tid], red[tid + s]);
        __syncthreads();
    }
    const float maxd = red[0];
    for (int n = tid; n < NN; n += 256) {
        const float ed = edstT[hd * NN + n];
        ed1T[hd * NN + n] = __expf(ed);
        ed2T[hd * NN + n] = __expf(0.2f * ed);
        const float es = esrcT[hd * NN + n];
        const float t  = es + maxd;
        const float M  = fmaxf(t, 0.2f * t);      // lrelu(es + max_j ed) >= any score
        es1T[hd * NN + n] = __expf(es - M);
        es2T[hd * NN + n] = __expf(0.2f * es - M);
    }
}

// ---- k3: full-row fused aggregation; bitmask in LDS, no in-loop barriers,
//          denominator completes in-block -> writes out directly ----
__global__ __launch_bounds__(256) void k3_attn(
        const uint32_t* __restrict__ bm, const unsigned short* __restrict__ whbT,
        const float* __restrict__ es1T, const float* __restrict__ es2T,
        const float* __restrict__ ed1T, const float* __restrict__ ed2T,
        const float* __restrict__ bias, float* __restrict__ out) {
    __shared__ uint32_t bmLds[BI * 129];    // row stride 129 words: conflict-free
    const int tid  = threadIdx.x;
    const int lane = tid & 63;
    const int wl   = tid >> 6;              // wave 0..3
    const int bx   = blockIdx.x;            // 512 blocks
    const int iblk = bx >> 1;
    const int hgrp = bx & 1;
    const int head = hgrp * 4 + wl;
    const int hf0  = head * FD;
    const int i0   = iblk * BI;
    const int g  = lane >> 4;
    const int lr = lane & 15;
    const int jrot = (bx & 7) * 512;        // per-XCD j-phase stagger (L2 window)

    // stage this block's 16 mask rows (8 KB) once
    #pragma unroll
    for (int u = 0; u < 8; ++u) {
        const int idx = u * 256 + tid;
        const int r = idx >> 7, w = idx & 127;
        bmLds[r * 129 + w] = bm[(size_t)(i0 + r) * 128 + w];
    }
    __syncthreads();

    const float es1 = es1T[head * NN + i0 + lr];
    const float es2 = es2T[head * NN + i0 + lr];
    float bs[4];
    #pragma unroll
    for (int ni = 0; ni < 4; ++ni) bs[ni] = bias[hf0 + ni * 16 + lr];

    floatx4 acc[4] = {};
    floatx4 accd = {};
    short8 ones;                            // all-ones B -> den in EVERY lane
    #pragma unroll
    for (int e = 0; e < 8; ++e) ones[e] = (short)0x3F80;

    const int wbase = lr * 129;
    for (int t = 0; t < NTILES; ++t) {
        const int j0 = (jrot + t * JT) & (NN - 1);
        const int wi = j0 >> 5;             // even; wi,wi+1 = this tile's words
        const uint32_t w0 = bmLds[wbase + wi];
        const uint32_t w1 = bmLds[wbase + wi + 1];

        short8 bfrag[2][4];
        #pragma unroll
        for (int ks = 0; ks < 2; ++ks)
            #pragma unroll
            for (int ni = 0; ni < 4; ++ni)
                bfrag[ks][ni] = *reinterpret_cast<const short8*>(
                    &whbT[(size_t)(hf0 + ni * 16 + lr) * NN + j0 + ks * 32 + g * 8]);

        #pragma unroll
        for (int ks = 0; ks < 2; ++ks) {
            const uint32_t b = ((ks ? w1 : w0) >> (g * 8)) & 0xFFu;
            const int jo = head * NN + j0 + ks * 32 + g * 8;
            const float4 e1a = *reinterpret_cast<const float4*>(&ed1T[jo]);
            const float4 e1b = *reinterpret_cast<const float4*>(&ed1T[jo + 4]);
            const float4 e2a = *reinterpret_cast<const float4*>(&ed2T[jo]);
            const float4 e2b = *reinterpret_cast<const float4*>(&ed2T[jo + 4]);
            union { uint32_t wd[4]; short8 s8; } pu;
            pu.wd[0] = packtrunc(fmaxf(es1 * e1a.x, es2 * e2a.x),
                                 fmaxf(es1 * e1a.y, es2 * e2a.y)) & bit2mask(b, 0);
            pu.wd[1] = packtrunc(fmaxf(es1 * e1a.z, es2 * e2a.z),
                                 fmaxf(es1 * e1a.w, es2 * e2a.w)) & bit2mask(b, 1);
            pu.wd[2] = packtrunc(fmaxf(es1 * e1b.x, es2 * e2b.x),
                                 fmaxf(es1 * e1b.y, es2 * e2b.y)) & bit2mask(b, 2);
            pu.wd[3] = packtrunc(fmaxf(es1 * e1b.z, es2 * e2b.z),
                                 fmaxf(es1 * e1b.w, es2 * e2b.w)) & bit2mask(b, 3);
            #pragma unroll
            for (int ni = 0; ni < 4; ++ni)
                acc[ni] = __builtin_amdgcn_mfma_f32_16x16x32_bf16(
                    pu.s8, bfrag[ks][ni], acc[ni], 0, 0, 0);
            accd = __builtin_amdgcn_mfma_f32_16x16x32_bf16(pu.s8, ones, accd, 0, 0, 0);
        }
    }

    // epilogue: normalize + bias, write out directly (den complete, all lanes)
    float inv[4];
    #pragma unroll
    for (int r = 0; r < 4; ++r) inv[r] = 1.0f / accd[r];
    #pragma unroll
    for (int ni = 0; ni < 4; ++ni)
        #pragma unroll
        for (int r = 0; r < 4; ++r)
            out[(size_t)(i0 + g * 4 + r) * HFD + hf0 + ni * 16 + lr] =
                acc[ni][r] * inv[r] + bs[ni];
}

extern "C" void kernel_launch(void* const* d_in, const int* in_sizes, int n_in,
                              void* d_out, int out_size, void* d_ws, size_t ws_size,
                              hipStream_t stream) {
    const float* hmat  = (const float*)d_in[0];
    const int*   adj   = (const int*)d_in[1];
    const float* Wmat  = (const float*)d_in[2];
    const float* a_src = (const float*)d_in[3];
    const float* a_dst = (const float*)d_in[4];
    const float* bias  = (const float*)d_in[5];
    float* out = (float*)d_out;

    char* ws = (char*)d_ws;
    unsigned short* whbT = (unsigned short*)ws;               // 4 MiB bf16 [HF][N]
    float* esrcT = (float*)(ws + (4u << 20));                 // 6 x 128 KiB tables
    float* edstT = esrcT + NH * NN;
    float* es1T  = edstT + NH * NN;
    float* es2T  = es1T + NH * NN;
    float* ed1T  = es2T + NH * NN;
    float* ed2T  = ed1T + NH * NN;
    uint32_t* bmk = (uint32_t*)(ed2T + NH * NN);              // 2 MiB bitmask
    unsigned short* h_hi = (unsigned short*)(bmk + (NN / 32) * NN); // 2 MiB
    unsigned short* h_lo = h_hi + (size_t)NN * KIN;           // 2 MiB
    unsigned short* wt_hi = h_lo + (size_t)NN * KIN;          // 256 KiB
    unsigned short* wt_lo = wt_hi + (size_t)KIN * HFD;        // 256 KiB

    k0_prep<<<dim3(3584), 256, 0, stream>>>(hmat, Wmat, adj, h_hi, h_lo, wt_hi, wt_lo, bmk);
    k1_front<<<dim3(64, 8), 256, 0, stream>>>(h_hi, h_lo, wt_hi, wt_lo, a_src, a_dst,
                                              whbT, esrcT, edstT);
    k2_tables<<<dim3(NH), 256, 0, stream>>>(esrcT, edstT, es1T, es2T, ed1T, ed2T);
    k3_attn<<<dim3(512), 256, 0, stream>>>(bmk, whbT, es1T, es2T, ed1T, ed2T, bias, out);
}